// Round 1
// baseline (760.029 us; speedup 1.0000x reference)
//
#include <hip/hip_runtime.h>
#include <hip/hip_bf16.h>

// Problem constants (from reference)
#define BATCH 16
#define SEQ_LEN 50
#define N_POINTS 25
#define SDF_H 100
#define SDF_W 100

// Scatter kernel: one thread per (b, t, p). Total B*T*P = 20000 threads.
// Reads x[b,t,2p], x[b,t,2p+1], resolution[b,t,0:2], origin[b,t,0:2];
// writes 1.0f at out[b, t, row, col, p].
__global__ void raster_scatter_kernel(const float* __restrict__ x,
                                      const float* __restrict__ resolution,
                                      const float* __restrict__ origin,
                                      float* __restrict__ out) {
    int gid = blockIdx.x * blockDim.x + threadIdx.x;
    const int total = BATCH * SEQ_LEN * N_POINTS;
    if (gid >= total) return;

    int p  = gid % N_POINTS;
    int bt = gid / N_POINTS;        // b*SEQ_LEN + t

    // x layout: (B, T, 2*P) -> element (bt, 2p) and (bt, 2p+1)
    const float px = x[bt * (2 * N_POINTS) + 2 * p];
    const float py = x[bt * (2 * N_POINTS) + 2 * p + 1];

    // resolution / origin layout: (B, T, 2)
    const float r0 = resolution[bt * 2 + 0];
    const float r1 = resolution[bt * 2 + 1];
    const float o0 = origin[bt * 2 + 0];
    const float o1 = origin[bt * 2 + 1];

    // Match reference: float32 divide + add, then truncate toward zero
    // (values are positive so trunc == floor). idx[...,0]=col, idx[...,1]=row.
    int col = (int)(px / r0 + o0);
    int row = (int)(py / r1 + o1);

    // Mirror JAX's clamping semantics for scatter indices (defensive; inputs
    // land in [25, 75) so this is normally a no-op).
    col = min(max(col, 0), SDF_W - 1);
    row = min(max(row, 0), SDF_H - 1);

    // out layout: (B, T, H, W, P)
    const size_t off =
        ((((size_t)bt * SDF_H + row) * SDF_W + col) * N_POINTS) + p;
    out[off] = 1.0f;
}

extern "C" void kernel_launch(void* const* d_in, const int* in_sizes, int n_in,
                              void* d_out, int out_size, void* d_ws, size_t ws_size,
                              hipStream_t stream) {
    const float* x          = (const float*)d_in[0];
    const float* resolution = (const float*)d_in[1];
    const float* origin     = (const float*)d_in[2];
    float* out = (float*)d_out;

    // 1) Zero the full output (harness poisons d_out with 0xAA every call).
    //    hipMemsetAsync is graph-capturable and uses the fast fill path.
    hipMemsetAsync(out, 0, (size_t)out_size * sizeof(float), stream);

    // 2) Scatter the 20000 ones.
    const int total = BATCH * SEQ_LEN * N_POINTS;
    const int block = 256;
    const int grid = (total + block - 1) / block;
    raster_scatter_kernel<<<grid, block, 0, stream>>>(x, resolution, origin, out);
}